// Round 1
// baseline (29.770 us; speedup 1.0000x reference)
//
#include <hip/hip_runtime.h>
#include <hip/hip_bf16.h>

// Reference collapse (T=1 decode):
//   causal = tril(ones(1, S)) -> only s=0 is unmasked; length >= 1 always,
//   so softmax probs == 1.0 exactly at s=0. Hence
//     attn[b,0,h,:] = bf16(cache_v_after_update[b, start, h, :])
//   with start = (kv_idx+1 - min(kv_idx+1, C)) % C, and the updated slot is
//   u = kv_idx % C. start == u only when kv_idx == 0 (fresh projection row).
//   Output y[b] = f32(bf16(v_sel[b])) @ wo + bo.   (q/k projections are dead.)

constexpr int BATCH = 16;
constexpr int FDIM  = 1024;   // F
constexpr int HD    = 1024;   // H*D
constexpr int CLEN  = 4096;   // C

__global__ __launch_bounds__(256) void mha_decode_collapsed(
    const float* __restrict__ x,        // [B,1,F]
    const int*   __restrict__ kv_idx,   // [B]
    const float* __restrict__ kv_value, // [B,C,H,D] = [B,C,HD]
    const float* __restrict__ wv,       // [F,H,D]   = [F,HD]
    const float* __restrict__ bv,       // [HD]
    const float* __restrict__ wo,       // [H,D,F]   = [HD,F]
    const float* __restrict__ bo,       // [F]
    float*       __restrict__ y)        // [B,1,F]
{
    const int b  = blockIdx.y;   // batch
    const int ft = blockIdx.x;   // f-tile (256 wide)
    const int t  = threadIdx.x;  // 0..255

    __shared__ float vsel[HD];   // bf16-rounded selected v row, as f32
    __shared__ float xs[FDIM];   // staged x row (projection path only)

    const int idx     = kv_idx[b];
    const int new_idx = idx + 1;
    const int length  = new_idx < CLEN ? new_idx : CLEN;
    const int pos0    = (new_idx - length) % CLEN;  // non-negative
    const int upd     = idx % CLEN;

    if (pos0 == upd) {
        // Rare path (kv_idx == 0): selected row is the fresh v projection.
        for (int f = t; f < FDIM; f += 256) xs[f] = x[b * FDIM + f];
        __syncthreads();
        const int j0 = t * 4;
        float a0 = 0.f, a1 = 0.f, a2 = 0.f, a3 = 0.f;
        for (int f = 0; f < FDIM; ++f) {
            const float xv = xs[f];
            const float4 w = *reinterpret_cast<const float4*>(&wv[(size_t)f * HD + j0]);
            a0 += xv * w.x; a1 += xv * w.y; a2 += xv * w.z; a3 += xv * w.w;
        }
        const float4 b4 = *reinterpret_cast<const float4*>(&bv[j0]);
        vsel[j0 + 0] = __bfloat162float(__float2bfloat16(a0 + b4.x));
        vsel[j0 + 1] = __bfloat162float(__float2bfloat16(a1 + b4.y));
        vsel[j0 + 2] = __bfloat162float(__float2bfloat16(a2 + b4.z));
        vsel[j0 + 3] = __bfloat162float(__float2bfloat16(a3 + b4.w));
    } else {
        // Common path: plain row read of kv_value, rounded through bf16.
        const float* src = kv_value + ((size_t)b * CLEN + (size_t)pos0) * HD;
        for (int j = t; j < HD; j += 256)
            vsel[j] = __bfloat162float(__float2bfloat16(src[j]));
    }
    __syncthreads();

    // y[b, f] = sum_j vsel[j] * wo[j, f] + bo[f]
    const int f = ft * 256 + t;
    float acc = bo[f];
#pragma unroll 8
    for (int j = 0; j < HD; ++j)
        acc += vsel[j] * wo[(size_t)j * FDIM + f];  // coalesced across lanes
    y[b * FDIM + f] = acc;
}

extern "C" void kernel_launch(void* const* d_in, const int* in_sizes, int n_in,
                              void* d_out, int out_size, void* d_ws, size_t ws_size,
                              hipStream_t stream) {
    // setup_inputs order:
    // 0:x 1:mask 2:kv_idx 3:kv_key 4:kv_value 5:wq 6:bq 7:wk 8:bk 9:wv 10:bv 11:wo 12:bo
    const float* x        = (const float*)d_in[0];
    const int*   kv_idx   = (const int*)  d_in[2];
    const float* kv_value = (const float*)d_in[4];
    const float* wv       = (const float*)d_in[9];
    const float* bv       = (const float*)d_in[10];
    const float* wo       = (const float*)d_in[11];
    const float* bo       = (const float*)d_in[12];
    float*       y        = (float*)d_out;

    dim3 grid(FDIM / 256, BATCH);  // (4 f-tiles, 16 batches)
    mha_decode_collapsed<<<grid, 256, 0, stream>>>(x, kv_idx, kv_value, wv, bv, wo, bo, y);
}

// Round 2
// 18.242 us; speedup vs baseline: 1.6319x; 1.6319x over previous
//
#include <hip/hip_runtime.h>
#include <hip/hip_bf16.h>

// Reference collapse (T=1 decode):
//   tril(ones(1,S)) keeps only s=0; length >= 1 always, so softmax == 1.0 at s=0.
//   attn[b,0,h,:] = bf16(cache_v_after_update[b, start, h, :]),
//   start = (kv_idx+1 - min(kv_idx+1, C)) % C; updated slot u = kv_idx % C.
//   start == u only when kv_idx == 0 (then row = x@wv + bv, bf16-rounded).
//   y[b] = f32(bf16(v_sel[b])) @ wo + bo.   q/k projections and the whole
//   QK^T/softmax are dead code.
//
// Kernel A: per-batch vsel row -> d_ws (f32, bf16-rounded), and y = bo init.
// Kernel B: Y += Vsel @ wo, wo reused across all 16 batches per block,
//           j split into 32 chunks, f32 atomicAdd partials.

constexpr int BATCH = 16;
constexpr int FDIM  = 1024;   // F
constexpr int HD    = 1024;   // H*D
constexpr int CLEN  = 4096;   // C
constexpr int JCHUNK = 32;    // j per block in kernel B
constexpr int NJ     = HD / JCHUNK;  // 32

__global__ __launch_bounds__(256) void vsel_and_init(
    const float* __restrict__ x,        // [B,1,F]
    const int*   __restrict__ kv_idx,   // [B]
    const float* __restrict__ kv_value, // [B,C,HD]
    const float* __restrict__ wv,       // [F,HD]
    const float* __restrict__ bv,       // [HD]
    const float* __restrict__ bo,       // [F]
    float*       __restrict__ vsel,     // [B,HD] in d_ws
    float*       __restrict__ y)        // [B,F]
{
    const int b = blockIdx.x;    // one block per batch
    const int t = threadIdx.x;   // 0..255

    const int idx     = kv_idx[b];
    const int new_idx = idx + 1;
    const int length  = new_idx < CLEN ? new_idx : CLEN;
    const int pos0    = (new_idx - length) % CLEN;  // non-negative
    const int upd     = idx % CLEN;

    if (pos0 == upd) {
        // Rare path (kv_idx == 0): selected row is the fresh v projection.
        __shared__ float xs[FDIM];
        for (int f = t; f < FDIM; f += 256) xs[f] = x[b * FDIM + f];
        __syncthreads();
        const int j0 = t * 4;
        float a0 = 0.f, a1 = 0.f, a2 = 0.f, a3 = 0.f;
        for (int f = 0; f < FDIM; ++f) {
            const float xv = xs[f];
            const float4 w = *reinterpret_cast<const float4*>(&wv[(size_t)f * HD + j0]);
            a0 += xv * w.x; a1 += xv * w.y; a2 += xv * w.z; a3 += xv * w.w;
        }
        const float4 b4 = *reinterpret_cast<const float4*>(&bv[j0]);
        float4 r;
        r.x = __bfloat162float(__float2bfloat16(a0 + b4.x));
        r.y = __bfloat162float(__float2bfloat16(a1 + b4.y));
        r.z = __bfloat162float(__float2bfloat16(a2 + b4.z));
        r.w = __bfloat162float(__float2bfloat16(a3 + b4.w));
        *reinterpret_cast<float4*>(&vsel[b * HD + j0]) = r;
    } else {
        // Common path: one row of kv_value, rounded through bf16.
        const float4* src = reinterpret_cast<const float4*>(
            kv_value + ((size_t)b * CLEN + (size_t)pos0) * HD);
        float4 v = src[t];  // 256 threads x 16B = 4KB row
        float4 r;
        r.x = __bfloat162float(__float2bfloat16(v.x));
        r.y = __bfloat162float(__float2bfloat16(v.y));
        r.z = __bfloat162float(__float2bfloat16(v.z));
        r.w = __bfloat162float(__float2bfloat16(v.w));
        reinterpret_cast<float4*>(&vsel[b * HD])[t] = r;
    }

    // Initialize y[b, :] = bo (atomicAdd partials land on top in kernel B).
#pragma unroll
    for (int f = t; f < FDIM; f += 256) y[b * FDIM + f] = bo[f];
}

__global__ __launch_bounds__(256) void gemv_wo(
    const float* __restrict__ vsel,  // [B,HD] in d_ws
    const float* __restrict__ wo,    // [HD,F]
    float*       __restrict__ y)     // [B,F], pre-initialized to bo
{
    const int t  = threadIdx.x;
    const int f  = blockIdx.x * 256 + t;   // output column
    const int j0 = blockIdx.y * JCHUNK;    // j-chunk base

    // Stage this block's wo panel in registers: 32 coalesced loads.
    float w[JCHUNK];
#pragma unroll
    for (int jj = 0; jj < JCHUNK; ++jj)
        w[jj] = wo[(size_t)(j0 + jj) * FDIM + f];

    float acc[BATCH];
#pragma unroll
    for (int b = 0; b < BATCH; ++b) acc[b] = 0.f;

    // vsel reads are block-uniform -> scalar loads; 16 FMAs per wo element.
#pragma unroll
    for (int b = 0; b < BATCH; ++b) {
        const float* vsb = vsel + b * HD + j0;
#pragma unroll
        for (int jj = 0; jj < JCHUNK; ++jj)
            acc[b] = fmaf(vsb[jj], w[jj], acc[b]);
    }

#pragma unroll
    for (int b = 0; b < BATCH; ++b)
        atomicAdd(&y[b * FDIM + f], acc[b]);
}

extern "C" void kernel_launch(void* const* d_in, const int* in_sizes, int n_in,
                              void* d_out, int out_size, void* d_ws, size_t ws_size,
                              hipStream_t stream) {
    // setup_inputs order:
    // 0:x 1:mask 2:kv_idx 3:kv_key 4:kv_value 5:wq 6:bq 7:wk 8:bk 9:wv 10:bv 11:wo 12:bo
    const float* x        = (const float*)d_in[0];
    const int*   kv_idx   = (const int*)  d_in[2];
    const float* kv_value = (const float*)d_in[4];
    const float* wv       = (const float*)d_in[9];
    const float* bv       = (const float*)d_in[10];
    const float* wo       = (const float*)d_in[11];
    const float* bo       = (const float*)d_in[12];
    float*       y        = (float*)d_out;
    float*       vsel     = (float*)d_ws;   // 16*1024*4 = 64 KB

    vsel_and_init<<<dim3(BATCH), 256, 0, stream>>>(x, kv_idx, kv_value, wv, bv, bo, vsel, y);
    gemv_wo<<<dim3(FDIM / 256, NJ), 256, 0, stream>>>(vsel, wo, y);
}

// Round 3
// 10.760 us; speedup vs baseline: 2.7666x; 1.6953x over previous
//
#include <hip/hip_runtime.h>
#include <hip/hip_bf16.h>

// Reference collapse (T=1 decode):
//   tril(ones(1,S)) keeps only s=0; length >= 1 always, so softmax == 1.0 at s=0.
//   attn[b,0,h,:] = bf16(cache_v_after_update[b, pos0, h, :]),
//   pos0 = (kv_idx+1 - min(kv_idx+1, C)) % C; updated slot u = kv_idx % C.
//   pos0 == u only when kv_idx == 0 (then row = bf16(x@wv + bv)).
//   y[b] = f32(bf16(v_sel[b])) @ wo + bo.  q/k/QK^T/softmax are dead code.
//
// Single fused dispatch: 256 blocks = 16 batches x 16 f-tiles(64 wide).
// Each block: recompute vsel row (4KB read), full-j GEMV slice with
// j split across 32 thread-groups, LDS partial reduce, plain store.
// bid = b*16 + ft  =>  bid%8 == ft%8: same f-tile lands on same XCD
// (round-robin dispatch), so wo panels are L2-resident across batches.

constexpr int BATCH = 16;
constexpr int FDIM  = 1024;   // F
constexpr int HD    = 1024;   // H*D
constexpr int CLEN  = 4096;   // C
constexpr int FT    = 64;     // f-columns per block
constexpr int NFT   = FDIM / FT;   // 16
constexpr int NJQ   = 32;     // j-quadrants (thread groups)
constexpr int JPT   = HD / NJQ;    // 32 j per thread

__global__ __launch_bounds__(1024) void mha_decode_fused(
    const float* __restrict__ x,        // [B,1,F]
    const int*   __restrict__ kv_idx,   // [B]
    const float* __restrict__ kv_value, // [B,C,HD]
    const float* __restrict__ wv,       // [F,HD]
    const float* __restrict__ bv,       // [HD]
    const float* __restrict__ wo,       // [HD,F]
    const float* __restrict__ bo,       // [F]
    float*       __restrict__ y)        // [B,F]
{
    const int bid = blockIdx.x;
    const int ft  = bid & (NFT - 1);   // f-tile; bid%8 == ft%8 -> XCD locality
    const int b   = bid >> 4;          // batch
    const int t   = threadIdx.x;       // 0..1023

    __shared__ float vsel[HD];          // bf16-rounded selected v row (f32)
    __shared__ float part[NJQ * FT];    // j-quadrant partials
    __shared__ float xs[FDIM];          // rare-path staging

    const int fl2 = t & 31;            // f-pair index within tile
    const int jq  = t >> 5;            // j-quadrant 0..31
    const int f0  = ft * FT + fl2 * 2;

    // ---- Issue all wo loads FIRST (independent of vsel) so their latency
    //      overlaps the kv_value row load + barrier. 32 x float2 = 64 VGPR.
    const float* wop = wo + (size_t)(jq * JPT) * FDIM + f0;
    float2 w[JPT];
#pragma unroll
    for (int i = 0; i < JPT; ++i)
        w[i] = *reinterpret_cast<const float2*>(wop + (size_t)i * FDIM);

    // ---- vsel row (each of the 1024 threads handles one element)
    const int idx     = kv_idx[b];
    const int new_idx = idx + 1;
    const int length  = new_idx < CLEN ? new_idx : CLEN;
    const int pos0    = (new_idx - length) % CLEN;  // non-negative
    const int upd     = idx % CLEN;

    if (pos0 == upd) {
        // Rare path (kv_idx == 0): fresh v projection row.
        xs[t] = x[b * FDIM + t];
        __syncthreads();
        float a = bv[t];
        for (int f = 0; f < FDIM; ++f)
            a = fmaf(xs[f], wv[(size_t)f * HD + t], a);
        vsel[t] = __bfloat162float(__float2bfloat16(a));
    } else {
        // Common path: one row of kv_value, rounded through bf16.
        const float v = kv_value[((size_t)b * CLEN + (size_t)pos0) * HD + t];
        vsel[t] = __bfloat162float(__float2bfloat16(v));
    }
    __syncthreads();

    // ---- GEMV slice: this thread covers j in [jq*32, jq*32+32)
    float a0 = 0.f, a1 = 0.f;
#pragma unroll
    for (int i = 0; i < JPT; ++i) {
        const float v = vsel[jq * JPT + i];   // same addr across half-wave: broadcast
        a0 = fmaf(v, w[i].x, a0);
        a1 = fmaf(v, w[i].y, a1);
    }
    part[jq * FT + fl2 * 2]     = a0;
    part[jq * FT + fl2 * 2 + 1] = a1;
    __syncthreads();

    // ---- Reduce 32 partials per f-column and store (2 lanes/bank: free)
    if (t < FT) {
        float acc = bo[ft * FT + t];
#pragma unroll
        for (int jj = 0; jj < NJQ; ++jj)
            acc += part[jj * FT + t];
        y[b * FDIM + ft * FT + t] = acc;
    }
}

extern "C" void kernel_launch(void* const* d_in, const int* in_sizes, int n_in,
                              void* d_out, int out_size, void* d_ws, size_t ws_size,
                              hipStream_t stream) {
    // setup_inputs order:
    // 0:x 1:mask 2:kv_idx 3:kv_key 4:kv_value 5:wq 6:bq 7:wk 8:bk 9:wv 10:bv 11:wo 12:bo
    const float* x        = (const float*)d_in[0];
    const int*   kv_idx   = (const int*)  d_in[2];
    const float* kv_value = (const float*)d_in[4];
    const float* wv       = (const float*)d_in[9];
    const float* bv       = (const float*)d_in[10];
    const float* wo       = (const float*)d_in[11];
    const float* bo       = (const float*)d_in[12];
    float*       y        = (float*)d_out;

    mha_decode_fused<<<dim3(BATCH * NFT), 1024, 0, stream>>>(
        x, kv_idx, kv_value, wv, bv, wo, bo, y);
}